// Round 1
// baseline (111.616 us; speedup 1.0000x reference)
//
#include <hip/hip_runtime.h>
#include <stdint.h>

// Problem constants (fixed shapes from setup_inputs):
//   X: [B=32, S=1024, H=2048] f32, idx: [B] i32
//   n_fixed = int(0.2*1024) = 204, n_rand = 820, p = 0.1f
constexpr int B = 32;
constexpr int S = 1024;
constexpr int H = 2048;
constexpr int H4 = H / 4;          // 512 float4 per row
constexpr int N_FIXED = 204;
constexpr int S_PER_BLOCK = 16;    // rows per block
constexpr int BLOCKS_PER_B = S / S_PER_BLOCK;  // 64

__device__ __forceinline__ uint32_t rotl32(uint32_t x, uint32_t d) {
    return (x << d) | (x >> (32u - d));
}

// JAX threefry2x32 (20 rounds), matches jax._src.prng.threefry2x32
__device__ __forceinline__ void threefry2x32(uint32_t k0, uint32_t k1,
                                             uint32_t x0, uint32_t x1,
                                             uint32_t& o0, uint32_t& o1) {
    const uint32_t ks0 = k0;
    const uint32_t ks1 = k1;
    const uint32_t ks2 = 0x1BD11BDAu ^ k0 ^ k1;

    x0 += ks0; x1 += ks1;

#define TF_R4(a, b, c, d)                               \
    x0 += x1; x1 = rotl32(x1, a); x1 ^= x0;             \
    x0 += x1; x1 = rotl32(x1, b); x1 ^= x0;             \
    x0 += x1; x1 = rotl32(x1, c); x1 ^= x0;             \
    x0 += x1; x1 = rotl32(x1, d); x1 ^= x0;

    TF_R4(13, 15, 26, 6)
    x0 += ks1; x1 += ks2 + 1u;
    TF_R4(17, 29, 16, 24)
    x0 += ks2; x1 += ks0 + 2u;
    TF_R4(13, 15, 26, 6)
    x0 += ks0; x1 += ks1 + 3u;
    TF_R4(17, 29, 16, 24)
    x0 += ks1; x1 += ks2 + 4u;
    TF_R4(13, 15, 26, 6)
    x0 += ks2; x1 += ks0 + 5u;
#undef TF_R4

    o0 = x0; o1 = x1;
}

// mask value for (example-id value `idv`, position s)
__device__ __forceinline__ float mask_val(uint32_t idv, int s) {
    if (s < N_FIXED) return 1.0f;
    const uint32_t j = (uint32_t)(s - N_FIXED);

    // fold_in(key(0), idv): threefry(key=(0,0), count=(0, idv))
    uint32_t k0, k1;
    threefry2x32(0u, 0u, 0u, idv, k0, k1);

    // partitionable random_bits (JAX >= 0.5 default):
    // bits[j] = e0 ^ e1 where (e0,e1) = threefry(key, (hi(j)=0, lo(j)=j))
    uint32_t e0, e1;
    threefry2x32(k0, k1, 0u, j, e0, e1);
    const uint32_t bits = e0 ^ e1;

    // uniform: bitcast((bits>>9) | 0x3F800000) - 1.0, then bernoulli: u < 0.1f
    const float u = __uint_as_float((bits >> 9) | 0x3F800000u) - 1.0f;
    return (u < 0.1f) ? 1.0f : 0.0f;
}

__global__ __launch_bounds__(256)
void tied_dropout_kernel(const float4* __restrict__ X,
                         const int* __restrict__ idx,
                         float4* __restrict__ out) {
    __shared__ float smask[S_PER_BLOCK];

    const int b = blockIdx.x / BLOCKS_PER_B;
    const int s_base = (blockIdx.x % BLOCKS_PER_B) * S_PER_BLOCK;
    const int t = threadIdx.x;

    if (t < S_PER_BLOCK) {
        smask[t] = mask_val((uint32_t)idx[b], s_base + t);
    }
    __syncthreads();

    // This block covers rows [s_base, s_base+16) of example b:
    // 16 rows * 512 float4 = 8192 float4; 256 threads -> 32 iterations.
    const size_t base = ((size_t)b * S + (size_t)s_base) * (size_t)H4;

#pragma unroll 8
    for (int it = 0; it < 32; ++it) {
        // f = it*256 + t; row within slab = f >> 9 = it >> 1 (uniform per iter)
        const float m = smask[it >> 1];
        const size_t f = base + (size_t)(it * 256 + t);
        float4 v = X[f];
        v.x *= m; v.y *= m; v.z *= m; v.w *= m;
        out[f] = v;
    }
}

extern "C" void kernel_launch(void* const* d_in, const int* in_sizes, int n_in,
                              void* d_out, int out_size, void* d_ws, size_t ws_size,
                              hipStream_t stream) {
    const float4* X = (const float4*)d_in[0];
    const int* idx = (const int*)d_in[1];
    float4* out = (float4*)d_out;

    const int grid = B * BLOCKS_PER_B;  // 2048 blocks
    tied_dropout_kernel<<<grid, 256, 0, stream>>>(X, idx, out);
}

// Round 3
// 99.694 us; speedup vs baseline: 1.1196x; 1.1196x over previous
//
#include <hip/hip_runtime.h>
#include <stdint.h>

// Problem constants (fixed shapes from setup_inputs):
//   X: [B=32, S=1024, H=2048] f32, idx: [B] i32
//   n_fixed = int(0.2*1024) = 204, n_rand = 820, p = 0.1f
constexpr int B = 32;
constexpr int S = 1024;
constexpr int H = 2048;
constexpr int H4 = H / 4;          // 512 float4 per row
constexpr int N_FIXED = 204;
constexpr int S_PER_BLOCK = 16;    // rows per block
constexpr int BLOCKS_PER_B = S / S_PER_BLOCK;  // 64

// clang-native vector type: __builtin_nontemporal_* requires a scalar /
// clang ext_vector pointer, not HIP's HIP_vector_type<float,4> class.
typedef float vf4 __attribute__((ext_vector_type(4)));

__device__ __forceinline__ uint32_t rotl32(uint32_t x, uint32_t d) {
    return (x << d) | (x >> (32u - d));
}

// JAX threefry2x32 (20 rounds), matches jax._src.prng.threefry2x32
__device__ __forceinline__ void threefry2x32(uint32_t k0, uint32_t k1,
                                             uint32_t x0, uint32_t x1,
                                             uint32_t& o0, uint32_t& o1) {
    const uint32_t ks0 = k0;
    const uint32_t ks1 = k1;
    const uint32_t ks2 = 0x1BD11BDAu ^ k0 ^ k1;

    x0 += ks0; x1 += ks1;

#define TF_R4(a, b, c, d)                               \
    x0 += x1; x1 = rotl32(x1, a); x1 ^= x0;             \
    x0 += x1; x1 = rotl32(x1, b); x1 ^= x0;             \
    x0 += x1; x1 = rotl32(x1, c); x1 ^= x0;             \
    x0 += x1; x1 = rotl32(x1, d); x1 ^= x0;

    TF_R4(13, 15, 26, 6)
    x0 += ks1; x1 += ks2 + 1u;
    TF_R4(17, 29, 16, 24)
    x0 += ks2; x1 += ks0 + 2u;
    TF_R4(13, 15, 26, 6)
    x0 += ks0; x1 += ks1 + 3u;
    TF_R4(17, 29, 16, 24)
    x0 += ks1; x1 += ks2 + 4u;
    TF_R4(13, 15, 26, 6)
    x0 += ks2; x1 += ks0 + 5u;
#undef TF_R4

    o0 = x0; o1 = x1;
}

// mask value for (example-id value `idv`, position s)
__device__ __forceinline__ float mask_val(uint32_t idv, int s) {
    if (s < N_FIXED) return 1.0f;
    const uint32_t j = (uint32_t)(s - N_FIXED);

    // fold_in(key(0), idv): threefry(key=(0,0), count=(0, idv))
    uint32_t k0, k1;
    threefry2x32(0u, 0u, 0u, idv, k0, k1);

    // partitionable random_bits (JAX >= 0.5 default):
    // bits[j] = e0 ^ e1 where (e0,e1) = threefry(key, (hi(j)=0, lo(j)=j))
    uint32_t e0, e1;
    threefry2x32(k0, k1, 0u, j, e0, e1);
    const uint32_t bits = e0 ^ e1;

    // uniform: bitcast((bits>>9) | 0x3F800000) - 1.0, then bernoulli: u < 0.1f
    const float u = __uint_as_float((bits >> 9) | 0x3F800000u) - 1.0f;
    return (u < 0.1f) ? 1.0f : 0.0f;
}

__global__ __launch_bounds__(256)
void tied_dropout_kernel(const vf4* __restrict__ X,
                         const int* __restrict__ idx,
                         vf4* __restrict__ out) {
    __shared__ float smask[S_PER_BLOCK];

    const int b = blockIdx.x / BLOCKS_PER_B;
    const int s_base = (blockIdx.x % BLOCKS_PER_B) * S_PER_BLOCK;
    const int t = threadIdx.x;

    if (t < S_PER_BLOCK) {
        smask[t] = mask_val((uint32_t)idx[b], s_base + t);
    }
    __syncthreads();

    // This block covers rows [s_base, s_base+16) of example b:
    // 16 rows * 512 float4 = 8192 float4; 256 threads -> 32 iterations.
    const size_t base = ((size_t)b * S + (size_t)s_base) * (size_t)H4;

#pragma unroll 8
    for (int it = 0; it < 32; ++it) {
        // f = it*256 + t; row within slab = f >> 9 = it >> 1 (uniform per iter)
        const float m = smask[it >> 1];
        const size_t f = base + (size_t)(it * 256 + t);
        // Streaming data, use-once in both directions: nontemporal
        // load/store sets the nt cache-bypass bits and avoids polluting
        // L1/L2 with 537 MB of dead lines.
        vf4 v = __builtin_nontemporal_load(&X[f]);
        v *= m;
        __builtin_nontemporal_store(v, &out[f]);
    }
}

extern "C" void kernel_launch(void* const* d_in, const int* in_sizes, int n_in,
                              void* d_out, int out_size, void* d_ws, size_t ws_size,
                              hipStream_t stream) {
    const vf4* X = (const vf4*)d_in[0];
    const int* idx = (const int*)d_in[1];
    vf4* out = (vf4*)d_out;

    const int grid = B * BLOCKS_PER_B;  // 2048 blocks
    tied_dropout_kernel<<<grid, 256, 0, stream>>>(X, idx, out);
}

// Round 4
// 97.057 us; speedup vs baseline: 1.1500x; 1.0272x over previous
//
#include <hip/hip_runtime.h>
#include <stdint.h>

// Problem constants (fixed shapes from setup_inputs):
//   X: [B=32, S=1024, H=2048] f32, idx: [B] i32
//   n_fixed = int(0.2*1024) = 204, n_rand = 820, p = 0.1f
constexpr int B = 32;
constexpr int S = 1024;
constexpr int H = 2048;
constexpr int H4 = H / 4;          // 512 float4 per row
constexpr int N_FIXED = 204;
constexpr int S_PER_BLOCK = 16;    // rows per block
constexpr int BLOCKS_PER_B = S / S_PER_BLOCK;  // 64

// clang-native vector type: __builtin_nontemporal_* requires a scalar /
// clang ext_vector pointer, not HIP's HIP_vector_type<float,4> class.
typedef float vf4 __attribute__((ext_vector_type(4)));

__device__ __forceinline__ uint32_t rotl32(uint32_t x, uint32_t d) {
    return (x << d) | (x >> (32u - d));
}

// JAX threefry2x32 (20 rounds), matches jax._src.prng.threefry2x32
__device__ __forceinline__ void threefry2x32(uint32_t k0, uint32_t k1,
                                             uint32_t x0, uint32_t x1,
                                             uint32_t& o0, uint32_t& o1) {
    const uint32_t ks0 = k0;
    const uint32_t ks1 = k1;
    const uint32_t ks2 = 0x1BD11BDAu ^ k0 ^ k1;

    x0 += ks0; x1 += ks1;

#define TF_R4(a, b, c, d)                               \
    x0 += x1; x1 = rotl32(x1, a); x1 ^= x0;             \
    x0 += x1; x1 = rotl32(x1, b); x1 ^= x0;             \
    x0 += x1; x1 = rotl32(x1, c); x1 ^= x0;             \
    x0 += x1; x1 = rotl32(x1, d); x1 ^= x0;

    TF_R4(13, 15, 26, 6)
    x0 += ks1; x1 += ks2 + 1u;
    TF_R4(17, 29, 16, 24)
    x0 += ks2; x1 += ks0 + 2u;
    TF_R4(13, 15, 26, 6)
    x0 += ks0; x1 += ks1 + 3u;
    TF_R4(17, 29, 16, 24)
    x0 += ks1; x1 += ks2 + 4u;
    TF_R4(13, 15, 26, 6)
    x0 += ks2; x1 += ks0 + 5u;
#undef TF_R4

    o0 = x0; o1 = x1;
}

// mask value for (example-id value `idv`, position s); exactly 0.0 or 1.0
__device__ __forceinline__ float mask_val(uint32_t idv, int s) {
    if (s < N_FIXED) return 1.0f;
    const uint32_t j = (uint32_t)(s - N_FIXED);

    // fold_in(key(0), idv): threefry(key=(0,0), count=(0, idv))
    uint32_t k0, k1;
    threefry2x32(0u, 0u, 0u, idv, k0, k1);

    // partitionable random_bits (JAX >= 0.5 default):
    // bits[j] = e0 ^ e1 where (e0,e1) = threefry(key, (hi(j)=0, lo(j)=j))
    uint32_t e0, e1;
    threefry2x32(k0, k1, 0u, j, e0, e1);
    const uint32_t bits = e0 ^ e1;

    // uniform: bitcast((bits>>9) | 0x3F800000) - 1.0, then bernoulli: u < 0.1f
    const float u = __uint_as_float((bits >> 9) | 0x3F800000u) - 1.0f;
    return (u < 0.1f) ? 1.0f : 0.0f;
}

__global__ __launch_bounds__(256)
void tied_dropout_kernel(const vf4* __restrict__ X,
                         const int* __restrict__ idx,
                         vf4* __restrict__ out) {
    __shared__ float smask[S_PER_BLOCK];

    const int b = blockIdx.x / BLOCKS_PER_B;
    const int s_base = (blockIdx.x % BLOCKS_PER_B) * S_PER_BLOCK;
    const int t = threadIdx.x;

    if (t < S_PER_BLOCK) {
        smask[t] = mask_val((uint32_t)idx[b], s_base + t);
    }
    __syncthreads();

    // Block covers rows [s_base, s_base+16) of example b:
    // 16 rows * 512 float4 = 8192 float4; 256 threads -> 32 iterations.
    // Row for iteration `it` is it>>1 for ALL threads (256 < 512/row), so
    // the mask test below is block-uniform: zero divergence.
    const size_t base = ((size_t)b * S + (size_t)s_base) * (size_t)H4;

#pragma unroll 8
    for (int it = 0; it < 32; ++it) {
        const float m = smask[it >> 1];
        const size_t f = base + (size_t)(it * 256 + t);
        if (m != 0.0f) {
            // kept row: mask is exactly 1.0 -> verbatim streaming copy
            vf4 v = __builtin_nontemporal_load(&X[f]);
            __builtin_nontemporal_store(v, &out[f]);
        } else {
            // dropped row (~72% of rows): output is zeros, skip the read
            vf4 z = (vf4)(0.0f);
            __builtin_nontemporal_store(z, &out[f]);
        }
    }
}

extern "C" void kernel_launch(void* const* d_in, const int* in_sizes, int n_in,
                              void* d_out, int out_size, void* d_ws, size_t ws_size,
                              hipStream_t stream) {
    const vf4* X = (const vf4*)d_in[0];
    const int* idx = (const int*)d_in[1];
    vf4* out = (vf4*)d_out;

    const int grid = B * BLOCKS_PER_B;  // 2048 blocks
    tied_dropout_kernel<<<grid, 256, 0, stream>>>(X, idx, out);
}

// Round 5
// 87.124 us; speedup vs baseline: 1.2811x; 1.1140x over previous
//
#include <hip/hip_runtime.h>
#include <stdint.h>

// Problem constants (fixed shapes from setup_inputs):
//   X: [B=32, S=1024, H=2048] f32, idx: [B] i32
//   n_fixed = int(0.2*1024) = 204, n_rand = 820, p = 0.1f
constexpr int B = 32;
constexpr int S = 1024;
constexpr int H = 2048;
constexpr int H4 = H / 4;          // 512 float4 per row
constexpr int N_FIXED = 204;
constexpr int S_PER_BLOCK = 16;    // rows per block
constexpr int BLOCKS_PER_B = S / S_PER_BLOCK;  // 64 residue classes

// clang-native vector type: __builtin_nontemporal_* requires a scalar /
// clang ext_vector pointer, not HIP's HIP_vector_type<float,4> class.
typedef float vf4 __attribute__((ext_vector_type(4)));

__device__ __forceinline__ uint32_t rotl32(uint32_t x, uint32_t d) {
    return (x << d) | (x >> (32u - d));
}

// JAX threefry2x32 (20 rounds), matches jax._src.prng.threefry2x32
__device__ __forceinline__ void threefry2x32(uint32_t k0, uint32_t k1,
                                             uint32_t x0, uint32_t x1,
                                             uint32_t& o0, uint32_t& o1) {
    const uint32_t ks0 = k0;
    const uint32_t ks1 = k1;
    const uint32_t ks2 = 0x1BD11BDAu ^ k0 ^ k1;

    x0 += ks0; x1 += ks1;

#define TF_R4(a, b, c, d)                               \
    x0 += x1; x1 = rotl32(x1, a); x1 ^= x0;             \
    x0 += x1; x1 = rotl32(x1, b); x1 ^= x0;             \
    x0 += x1; x1 = rotl32(x1, c); x1 ^= x0;             \
    x0 += x1; x1 = rotl32(x1, d); x1 ^= x0;

    TF_R4(13, 15, 26, 6)
    x0 += ks1; x1 += ks2 + 1u;
    TF_R4(17, 29, 16, 24)
    x0 += ks2; x1 += ks0 + 2u;
    TF_R4(13, 15, 26, 6)
    x0 += ks0; x1 += ks1 + 3u;
    TF_R4(17, 29, 16, 24)
    x0 += ks1; x1 += ks2 + 4u;
    TF_R4(13, 15, 26, 6)
    x0 += ks2; x1 += ks0 + 5u;
#undef TF_R4

    o0 = x0; o1 = x1;
}

// mask value for (example-id value `idv`, position s); exactly 0.0 or 1.0
__device__ __forceinline__ float mask_val(uint32_t idv, int s) {
    if (s < N_FIXED) return 1.0f;
    const uint32_t j = (uint32_t)(s - N_FIXED);

    // fold_in(key(0), idv): threefry(key=(0,0), count=(0, idv))
    uint32_t k0, k1;
    threefry2x32(0u, 0u, 0u, idv, k0, k1);

    // partitionable random_bits (JAX >= 0.5 default):
    // bits[j] = e0 ^ e1 where (e0,e1) = threefry(key, (hi(j)=0, lo(j)=j))
    uint32_t e0, e1;
    threefry2x32(k0, k1, 0u, j, e0, e1);
    const uint32_t bits = e0 ^ e1;

    // uniform: bitcast((bits>>9) | 0x3F800000) - 1.0, then bernoulli: u < 0.1f
    const float u = __uint_as_float((bits >> 9) | 0x3F800000u) - 1.0f;
    return (u < 0.1f) ? 1.0f : 0.0f;
}

__global__ __launch_bounds__(256)
void tied_dropout_kernel(const vf4* __restrict__ X,
                         const int* __restrict__ idx,
                         vf4* __restrict__ out) {
    __shared__ float smask[S_PER_BLOCK];

    const int b = blockIdx.x / BLOCKS_PER_B;     // example
    const int slab = blockIdx.x % BLOCKS_PER_B;  // residue class mod 64
    const int t = threadIdx.x;

    // LOAD BALANCE: block covers rows {slab + 64*j, j=0..15}. Always-kept
    // rows (s < 204, read+write) are rows 0..203 -> every residue class
    // holds 3-4 of them, so every block (hence every CU) gets the same
    // heavy/light mix. The previous contiguous-slab mapping put ALL heavy
    // blocks on CUs with c%64 < 13 (52 CUs did 2x the traffic -> 97 us tail).
    if (t < S_PER_BLOCK) {
        smask[t] = mask_val((uint32_t)idx[b], slab + t * 64);
    }
    __syncthreads();

    const size_t ebase = (size_t)b * S * H4;

#pragma unroll 8
    for (int it = 0; it < 32; ++it) {
        // row j = it>>1 (block-uniform), half h = it&1
        const int j = it >> 1;
        const float m = smask[j];
        const int s = slab + j * 64;
        const size_t f = ebase + (size_t)s * H4 + (size_t)((it & 1) * 256 + t);
        if (m != 0.0f) {
            // kept row: mask is exactly 1.0 -> verbatim streaming copy
            vf4 v = __builtin_nontemporal_load(&X[f]);
            __builtin_nontemporal_store(v, &out[f]);
        } else {
            // dropped row (~72%): output is zeros, skip the read
            vf4 z = (vf4)(0.0f);
            __builtin_nontemporal_store(z, &out[f]);
        }
    }
}

extern "C" void kernel_launch(void* const* d_in, const int* in_sizes, int n_in,
                              void* d_out, int out_size, void* d_ws, size_t ws_size,
                              hipStream_t stream) {
    const vf4* X = (const vf4*)d_in[0];
    const int* idx = (const int*)d_in[1];
    vf4* out = (vf4*)d_out;

    const int grid = B * BLOCKS_PER_B;  // 2048 blocks, 8 per CU, all resident
    tied_dropout_kernel<<<grid, 256, 0, stream>>>(X, idx, out);
}

// Round 6
// 71.932 us; speedup vs baseline: 1.5517x; 1.2112x over previous
//
#include <hip/hip_runtime.h>
#include <stdint.h>

// Problem constants (fixed shapes from setup_inputs):
//   X: [B=32, S=1024, H=2048] f32, idx: [B] i32
//   n_fixed = int(0.2*1024) = 204, n_rand = 820, p = 0.1f
constexpr int B = 32;
constexpr int S = 1024;
constexpr int H = 2048;
constexpr int H4 = H / 4;          // 512 float4 per row
constexpr int N_FIXED = 204;
constexpr int S_PER_BLOCK = 16;    // rows per block
constexpr int BLOCKS_PER_B = S / S_PER_BLOCK;  // 64 residue classes

// clang-native vector type: __builtin_nontemporal_* requires a scalar /
// clang ext_vector pointer, not HIP's HIP_vector_type<float,4> class.
typedef float vf4 __attribute__((ext_vector_type(4)));

__device__ __forceinline__ uint32_t rotl32(uint32_t x, uint32_t d) {
    return (x << d) | (x >> (32u - d));
}

// JAX threefry2x32 (20 rounds), matches jax._src.prng.threefry2x32
__device__ __forceinline__ void threefry2x32(uint32_t k0, uint32_t k1,
                                             uint32_t x0, uint32_t x1,
                                             uint32_t& o0, uint32_t& o1) {
    const uint32_t ks0 = k0;
    const uint32_t ks1 = k1;
    const uint32_t ks2 = 0x1BD11BDAu ^ k0 ^ k1;

    x0 += ks0; x1 += ks1;

#define TF_R4(a, b, c, d)                               \
    x0 += x1; x1 = rotl32(x1, a); x1 ^= x0;             \
    x0 += x1; x1 = rotl32(x1, b); x1 ^= x0;             \
    x0 += x1; x1 = rotl32(x1, c); x1 ^= x0;             \
    x0 += x1; x1 = rotl32(x1, d); x1 ^= x0;

    TF_R4(13, 15, 26, 6)
    x0 += ks1; x1 += ks2 + 1u;
    TF_R4(17, 29, 16, 24)
    x0 += ks2; x1 += ks0 + 2u;
    TF_R4(13, 15, 26, 6)
    x0 += ks0; x1 += ks1 + 3u;
    TF_R4(17, 29, 16, 24)
    x0 += ks1; x1 += ks2 + 4u;
    TF_R4(13, 15, 26, 6)
    x0 += ks2; x1 += ks0 + 5u;
#undef TF_R4

    o0 = x0; o1 = x1;
}

// mask value for (example-id value `idv`, position s); exactly 0.0 or 1.0
__device__ __forceinline__ float mask_val(uint32_t idv, int s) {
    if (s < N_FIXED) return 1.0f;
    const uint32_t j = (uint32_t)(s - N_FIXED);

    // fold_in(key(0), idv): threefry(key=(0,0), count=(0, idv))
    uint32_t k0, k1;
    threefry2x32(0u, 0u, 0u, idv, k0, k1);

    // partitionable random_bits (JAX >= 0.5 default):
    // bits[j] = e0 ^ e1 where (e0,e1) = threefry(key, (hi(j)=0, lo(j)=j))
    uint32_t e0, e1;
    threefry2x32(k0, k1, 0u, j, e0, e1);
    const uint32_t bits = e0 ^ e1;

    // uniform: bitcast((bits>>9) | 0x3F800000) - 1.0, then bernoulli: u < 0.1f
    const float u = __uint_as_float((bits >> 9) | 0x3F800000u) - 1.0f;
    return (u < 0.1f) ? 1.0f : 0.0f;
}

__global__ __launch_bounds__(256)
void tied_dropout_kernel(const vf4* __restrict__ X,
                         const int* __restrict__ idx,
                         vf4* __restrict__ out) {
    __shared__ float smask[S_PER_BLOCK];

    const int b = blockIdx.x / BLOCKS_PER_B;     // example
    const int slab = blockIdx.x % BLOCKS_PER_B;  // residue class mod 64
    const int t = threadIdx.x;

    // LOAD BALANCE: block covers rows {slab + 64*j, j=0..15}; every residue
    // class holds 3-4 always-kept rows, so every CU gets the same mix.
    if (t < S_PER_BLOCK) {
        smask[t] = mask_val((uint32_t)idx[b], slab + t * 64);
    }
    __syncthreads();

    const size_t ebase = (size_t)b * S * H4;

#pragma unroll 8
    for (int it = 0; it < 32; ++it) {
        // row j = it>>1 (block-uniform), half h = it&1
        const int j = it >> 1;
        const float m = smask[j];
        const int s = slab + j * 64;
        const size_t f = ebase + (size_t)s * H4 + (size_t)((it & 1) * 256 + t);
        if (m != 0.0f) {
            // kept row: mask is exactly 1.0 -> verbatim copy.
            // NT load: use-once read, bypass L1/L2 (R3 evidence: helps).
            // REGULAR store: NT stores bypassed L2 write-combining and
            // capped the write stream at ~3.1 TB/s (R5: 268MB/87us) vs
            // ~7 TB/s for the regular-store path (fill kernels).
            vf4 v = __builtin_nontemporal_load(&X[f]);
            out[f] = v;
        } else {
            // dropped row (~72%): output is zeros, skip the read
            out[f] = (vf4)(0.0f);
        }
    }
}

extern "C" void kernel_launch(void* const* d_in, const int* in_sizes, int n_in,
                              void* d_out, int out_size, void* d_ws, size_t ws_size,
                              hipStream_t stream) {
    const vf4* X = (const vf4*)d_in[0];
    const int* idx = (const int*)d_in[1];
    vf4* out = (vf4*)d_out;

    const int grid = B * BLOCKS_PER_B;  // 2048 blocks, 8 per CU, all resident
    tied_dropout_kernel<<<grid, 256, 0, stream>>>(X, idx, out);
}

// Round 7
// 54.609 us; speedup vs baseline: 2.0439x; 1.3172x over previous
//
#include <hip/hip_runtime.h>
#include <stdint.h>

// Problem constants (fixed shapes from setup_inputs):
//   X: [B=32, S=1024, H=2048] f32, idx: [B] i32
//   n_fixed = int(0.2*1024) = 204, n_rand = 820, p = 0.1f
constexpr int B = 32;
constexpr int S = 1024;
constexpr int H = 2048;
constexpr int H4 = H / 4;          // 512 float4 per row
constexpr int N_FIXED = 204;
constexpr int S_PER_BLOCK = 16;    // rows per block
constexpr int BLOCKS_PER_B = S / S_PER_BLOCK;  // 64 residue classes

// clang-native vector type: __builtin_nontemporal_* requires a scalar /
// clang ext_vector pointer, not HIP's HIP_vector_type<float,4> class.
typedef float vf4 __attribute__((ext_vector_type(4)));

__device__ __forceinline__ uint32_t rotl32(uint32_t x, uint32_t d) {
    return (x << d) | (x >> (32u - d));
}

// JAX threefry2x32 (20 rounds), matches jax._src.prng.threefry2x32
__device__ __forceinline__ void threefry2x32(uint32_t k0, uint32_t k1,
                                             uint32_t x0, uint32_t x1,
                                             uint32_t& o0, uint32_t& o1) {
    const uint32_t ks0 = k0;
    const uint32_t ks1 = k1;
    const uint32_t ks2 = 0x1BD11BDAu ^ k0 ^ k1;

    x0 += ks0; x1 += ks1;

#define TF_R4(a, b, c, d)                               \
    x0 += x1; x1 = rotl32(x1, a); x1 ^= x0;             \
    x0 += x1; x1 = rotl32(x1, b); x1 ^= x0;             \
    x0 += x1; x1 = rotl32(x1, c); x1 ^= x0;             \
    x0 += x1; x1 = rotl32(x1, d); x1 ^= x0;

    TF_R4(13, 15, 26, 6)
    x0 += ks1; x1 += ks2 + 1u;
    TF_R4(17, 29, 16, 24)
    x0 += ks2; x1 += ks0 + 2u;
    TF_R4(13, 15, 26, 6)
    x0 += ks0; x1 += ks1 + 3u;
    TF_R4(17, 29, 16, 24)
    x0 += ks1; x1 += ks2 + 4u;
    TF_R4(13, 15, 26, 6)
    x0 += ks2; x1 += ks0 + 5u;
#undef TF_R4

    o0 = x0; o1 = x1;
}

// mask value for (example-id value `idv`, position s); exactly 0.0 or 1.0
__device__ __forceinline__ float mask_val(uint32_t idv, int s) {
    if (s < N_FIXED) return 1.0f;
    const uint32_t j = (uint32_t)(s - N_FIXED);

    // fold_in(key(0), idv): threefry(key=(0,0), count=(0, idv))
    uint32_t k0, k1;
    threefry2x32(0u, 0u, 0u, idv, k0, k1);

    // partitionable random_bits (JAX >= 0.5 default):
    // bits[j] = e0 ^ e1 where (e0,e1) = threefry(key, (hi(j)=0, lo(j)=j))
    uint32_t e0, e1;
    threefry2x32(k0, k1, 0u, j, e0, e1);
    const uint32_t bits = e0 ^ e1;

    // uniform: bitcast((bits>>9) | 0x3F800000) - 1.0, then bernoulli: u < 0.1f
    const float u = __uint_as_float((bits >> 9) | 0x3F800000u) - 1.0f;
    return (u < 0.1f) ? 1.0f : 0.0f;
}

__global__ __launch_bounds__(256)
void tied_dropout_kernel(const vf4* __restrict__ X,
                         const int* __restrict__ idx,
                         vf4* __restrict__ out) {
    __shared__ float smask[S_PER_BLOCK];

    const int b = blockIdx.x / BLOCKS_PER_B;     // example
    const int slab = blockIdx.x % BLOCKS_PER_B;  // residue class mod 64
    const int t = threadIdx.x;

    // LOAD BALANCE: block covers rows {slab + 64*j, j=0..15}; every residue
    // class holds 3-4 always-kept rows, so every CU gets the same mix.
    if (t < S_PER_BLOCK) {
        smask[t] = mask_val((uint32_t)idx[b], slab + t * 64);
    }
    __syncthreads();

    // Pack kept/dropped row sets into bitmasks (register-only iteration via
    // ctz — no runtime-indexed arrays, no scratch).
    uint32_t keep = 0;
#pragma unroll
    for (int j = 0; j < S_PER_BLOCK; ++j) {
        keep |= (smask[j] != 0.0f ? 1u : 0u) << j;
    }
    uint32_t dropm = ~keep & 0xFFFFu;

    // Row j covers vf4 range [rbase, rbase+512), rbase = ebase + j*64*H4;
    // thread t handles elements rbase+t and rbase+t+256 (two 4KB halves).
    const size_t ebase = ((size_t)b * S + (size_t)slab) * (size_t)H4;

    // PHASE 1 — dropped rows (~72%): pure dependency-free write stream.
    // No reads mixed in -> fill-like HBM behavior (~7 TB/s observed).
    const vf4 z = (vf4)(0.0f);
    {
        uint32_t m = dropm;
        while (m) {
            const int j = __builtin_ctz(m);
            m &= m - 1;
            const size_t r = ebase + (size_t)(j * 64) * H4 + (size_t)t;
            out[r] = z;
            out[r + 256] = z;
        }
    }

    // PHASE 2 — kept rows (~28%): straight-line copy, both halves' NT loads
    // issued before the stores so the compiler batches loads then stores.
    {
        uint32_t m = keep;
        while (m) {
            const int j = __builtin_ctz(m);
            m &= m - 1;
            const size_t r = ebase + (size_t)(j * 64) * H4 + (size_t)t;
            vf4 a = __builtin_nontemporal_load(&X[r]);
            vf4 c = __builtin_nontemporal_load(&X[r + 256]);
            out[r] = a;
            out[r + 256] = c;
        }
    }
}

extern "C" void kernel_launch(void* const* d_in, const int* in_sizes, int n_in,
                              void* d_out, int out_size, void* d_ws, size_t ws_size,
                              hipStream_t stream) {
    const vf4* X = (const vf4*)d_in[0];
    const int* idx = (const int*)d_in[1];
    vf4* out = (vf4*)d_out;

    const int grid = B * BLOCKS_PER_B;  // 2048 blocks, 8 per CU, all resident
    tied_dropout_kernel<<<grid, 256, 0, stream>>>(X, idx, out);
}